// Round 2
// baseline (1037.315 us; speedup 1.0000x reference)
//
#include <hip/hip_runtime.h>
#include <hip/hip_bf16.h>

typedef __bf16 bf16;
typedef __bf16 bf16x8 __attribute__((ext_vector_type(8)));
typedef float f32x4 __attribute__((ext_vector_type(4)));
typedef float floatv4 __attribute__((ext_vector_type(4)));

#define QK_SCALE 0.17677669529663687f

// ---- swizzled LDS addressing -------------------------------------------------
// qp/k tiles: [64][32] bf16 per head (row = 64B = 4 x 16B chunks).
// chunk' = chunk ^ ((row>>1)&3): wave-read (16 rows x 4 chunk-cols) -> 2-way = free.
__device__ __forceinline__ bf16* qk_ptr(bf16* base, int row, int col) {
    return base + row * 32 + ((((col >> 3) ^ ((row >> 1) & 3)) << 3)) + (col & 7);
}
// vt tile: [32][64] bf16 per head (row = 128B = 8 chunks). chunk' = chunk ^ (row&7).
__device__ __forceinline__ bf16* vt_ptr(bf16* base, int row, int col) {
    return base + row * 64 + ((((col >> 3) ^ (row & 7)) << 3)) + (col & 7);
}
// ao tile: [64][192] bf16 (row = 384B = 24 chunks). chunk' = chunk ^ (row&7)
// (XOR<=7 stays inside the same 8-chunk block, so chunk' < 24 always).
__device__ __forceinline__ bf16* ao_ptr(bf16* base, int row, int col) {
    return base + row * 192 + ((((col >> 3) ^ (row & 7)) << 3)) + (col & 7);
}

// ---------------- pre-kernel: weight bf16 convert + rpb expand ----------------
__global__ void wmsa_prep(const float* __restrict__ qkv_w,
                          const float* __restrict__ out_w,
                          const float* __restrict__ rpb_table,
                          bf16* __restrict__ qkv_wb,
                          bf16* __restrict__ out_wb,
                          float* __restrict__ rpbx) {
    int t = blockIdx.x * 256 + threadIdx.x;
    if (t < 110592) qkv_wb[t] = (bf16)qkv_w[t];
    if (t < 36864)  out_wb[t] = (bf16)out_w[t];
    if (t < 14406) {
        int h = t / 2401, ij = t % 2401, i = ij / 49, j = ij % 49;
        int ri = (i / 7 - j / 7 + 6) * 13 + (i % 7 - j % 7 + 6);
        rpbx[t] = rpb_table[ri * 6 + h];
    }
}

// ---------------- main fused kernel: one window per block ----------------
__global__ __launch_bounds__(384, 3) void wmsa_main(
    const float* __restrict__ x, const float* __restrict__ mask,
    const float* __restrict__ qkv_b, const float* __restrict__ out_b,
    const bf16* __restrict__ qkv_wb, const bf16* __restrict__ out_wb,
    const float* __restrict__ rpbx, float* __restrict__ out)
{
    // q (later p): 6 heads x [64][32]; k (later ao[64][192]); v^T: 6 x [32][64]
    __shared__ bf16 s_qp[6][2048];
    __shared__ bf16 s_kao[12288];
    __shared__ bf16 s_vt[6][2048];

    const int b    = blockIdx.x;
    const int tid  = threadIdx.x;
    const int wv   = tid >> 6;      // 0..5
    const int lane = tid & 63;
    const int lo   = lane & 15;
    const int hi   = lane >> 4;     // 0..3

    const float* xw    = x + (size_t)b * 9408;
    const int    obase = wv * 96;
    const int    sec   = wv >> 1;   // 0=q 1=k 2=v

    // ============ Phase 1: QKV = x @ qkv_w^T + qkv_b (mi-blocked) ============
#pragma unroll 1
    for (int mib = 0; mib < 2; ++mib) {
        f32x4 acc[2][6];
#pragma unroll
        for (int mi = 0; mi < 2; ++mi)
#pragma unroll
            for (int nj = 0; nj < 6; ++nj) acc[mi][nj] = (f32x4){0.f, 0.f, 0.f, 0.f};

        const int r0 = mib * 32 + lo;        // always < 49
        const int r1 = r0 + 16;              // mib=1: valid only if < 49

        auto loadA = [&](bf16x8& d0, bf16x8& d1, int kk) {
            const float* p0 = xw + r0 * 192 + kk * 32 + hi * 8;
            floatv4 f0 = *(const floatv4*)p0;
            floatv4 f1 = *(const floatv4*)(p0 + 4);
            d0[0]=(bf16)f0[0]; d0[1]=(bf16)f0[1]; d0[2]=(bf16)f0[2]; d0[3]=(bf16)f0[3];
            d0[4]=(bf16)f1[0]; d0[5]=(bf16)f1[1]; d0[6]=(bf16)f1[2]; d0[7]=(bf16)f1[3];
            floatv4 g0 = {0.f,0.f,0.f,0.f}, g1 = {0.f,0.f,0.f,0.f};
            if (r1 < 49) {
                const float* p1 = xw + r1 * 192 + kk * 32 + hi * 8;
                g0 = *(const floatv4*)p1;
                g1 = *(const floatv4*)(p1 + 4);
            }
            d1[0]=(bf16)g0[0]; d1[1]=(bf16)g0[1]; d1[2]=(bf16)g0[2]; d1[3]=(bf16)g0[3];
            d1[4]=(bf16)g1[0]; d1[5]=(bf16)g1[1]; d1[6]=(bf16)g1[2]; d1[7]=(bf16)g1[3];
        };
        auto loadB = [&](bf16x8* dst, int kk) {
#pragma unroll
            for (int nj = 0; nj < 6; ++nj) {
                const int o = obase + nj * 16 + lo;
                dst[nj] = *(const bf16x8*)(qkv_wb + o * 192 + kk * 32 + hi * 8);
            }
        };
        auto step = [&](bf16x8 a0, bf16x8 a1, bf16x8* bfr) {
#pragma unroll
            for (int nj = 0; nj < 6; ++nj) {
                acc[0][nj] = __builtin_amdgcn_mfma_f32_16x16x32_bf16(a0, bfr[nj], acc[0][nj], 0, 0, 0);
                acc[1][nj] = __builtin_amdgcn_mfma_f32_16x16x32_bf16(a1, bfr[nj], acc[1][nj], 0, 0, 0);
            }
        };

        bf16x8 a0A, a1A, a0B, a1B, bA[6], bB[6];
        loadA(a0A, a1A, 0); loadB(bA, 0);
        loadA(a0B, a1B, 1); loadB(bB, 1);
        step(a0A, a1A, bA);
        loadA(a0A, a1A, 2); loadB(bA, 2);
        step(a0B, a1B, bB);
        loadA(a0B, a1B, 3); loadB(bB, 3);
        step(a0A, a1A, bA);
        loadA(a0A, a1A, 4); loadB(bA, 4);
        step(a0B, a1B, bB);
        loadA(a0B, a1B, 5); loadB(bB, 5);
        step(a0A, a1A, bA);
        step(a0B, a1B, bB);

        // epilogue: bias + scatter into q / k / v^T LDS tiles
#pragma unroll
        for (int nj = 0; nj < 6; ++nj) {
            const int o    = obase + nj * 16 + lo;
            const float bs = qkv_b[o];
            const int oc   = o - sec * 192;
            const int hh   = oc >> 5;
            const int dd   = oc & 31;
#pragma unroll
            for (int mi = 0; mi < 2; ++mi)
#pragma unroll
                for (int r = 0; r < 4; ++r) {
                    const int n = mib * 32 + mi * 16 + hi * 4 + r;
                    const float v = acc[mi][nj][r] + bs;
                    if (sec == 0)      *qk_ptr(&s_qp[hh][0], n, dd)     = (bf16)(v * QK_SCALE);
                    else if (sec == 1) *qk_ptr(s_kao + hh * 2048, n, dd) = (bf16)v;
                    else               *vt_ptr(&s_vt[hh][0], dd, n)     = (bf16)v;
                }
        }
    }
    __syncthreads();

    // ============ Phase 2: attention, head h = wave id ============
    {
        const int h = wv;
        bf16* qb = &s_qp[h][0];
        bf16* kb_base = s_kao + h * 2048;

        bf16x8 qa[4], kb[4];
#pragma unroll
        for (int mi = 0; mi < 4; ++mi)
            qa[mi] = *(const bf16x8*)qk_ptr(qb, mi * 16 + lo, hi * 8);
#pragma unroll
        for (int nt = 0; nt < 4; ++nt)
            kb[nt] = *(const bf16x8*)qk_ptr(kb_base, nt * 16 + lo, hi * 8);
        __syncthreads();   // all waves' q/k reads done -> safe to overlay p/ao

        f32x4 s[4][4];
#pragma unroll
        for (int mi = 0; mi < 4; ++mi)
#pragma unroll
            for (int nt = 0; nt < 4; ++nt) s[mi][nt] = (f32x4){0.f, 0.f, 0.f, 0.f};
#pragma unroll
        for (int mi = 0; mi < 4; ++mi)
#pragma unroll
            for (int nt = 0; nt < 4; ++nt)
                s[mi][nt] = __builtin_amdgcn_mfma_f32_16x16x32_bf16(
                    qa[mi], kb[nt], s[mi][nt], 0, 0, 0);

        // bias + mask; kill padded key columns
        const float* mk = mask + (size_t)(b & 63) * 2401;
        const float* rb = rpbx + h * 2401;
#pragma unroll
        for (int nt = 0; nt < 4; ++nt) {
            const int j = nt * 16 + lo;
#pragma unroll
            for (int mi = 0; mi < 4; ++mi)
#pragma unroll
                for (int r = 0; r < 4; ++r) {
                    const int i = mi * 16 + hi * 4 + r;
                    float sv = s[mi][nt][r];
                    if (j >= 49) sv = -1e30f;
                    else if (i < 49) sv += rb[i * 49 + j] + mk[i * 49 + j];
                    s[mi][nt][r] = sv;
                }
        }

        // softmax over j (64 cols = 4 regs x 16 lanes sharing hi)
#pragma unroll
        for (int mi = 0; mi < 4; ++mi)
#pragma unroll
            for (int r = 0; r < 4; ++r) {
                float m = fmaxf(fmaxf(s[mi][0][r], s[mi][1][r]),
                                fmaxf(s[mi][2][r], s[mi][3][r]));
                m = fmaxf(m, __shfl_xor(m, 1));
                m = fmaxf(m, __shfl_xor(m, 2));
                m = fmaxf(m, __shfl_xor(m, 4));
                m = fmaxf(m, __shfl_xor(m, 8));
                float sum = 0.f;
#pragma unroll
                for (int nt = 0; nt < 4; ++nt) {
                    float p = __expf(s[mi][nt][r] - m);
                    s[mi][nt][r] = p;
                    sum += p;
                }
                sum += __shfl_xor(sum, 1);
                sum += __shfl_xor(sum, 2);
                sum += __shfl_xor(sum, 4);
                sum += __shfl_xor(sum, 8);
                const float inv = 1.0f / sum;
#pragma unroll
                for (int nt = 0; nt < 4; ++nt) s[mi][nt][r] *= inv;
            }

        // PV: O_h = P(64x64) @ V_h(64x32); P staged into qp[h] (q is dead)
        f32x4 oacc[4][2];
#pragma unroll
        for (int mi = 0; mi < 4; ++mi)
#pragma unroll
            for (int nd = 0; nd < 2; ++nd) oacc[mi][nd] = (f32x4){0.f, 0.f, 0.f, 0.f};

#pragma unroll 1
        for (int kk = 0; kk < 2; ++kk) {
#pragma unroll
            for (int mi = 0; mi < 4; ++mi)
#pragma unroll
                for (int c = 0; c < 2; ++c) {
                    const int nt = kk * 2 + c;
#pragma unroll
                    for (int r = 0; r < 4; ++r)
                        *qk_ptr(qb, mi * 16 + hi * 4 + r, c * 16 + lo) = (bf16)s[mi][nt][r];
                }
            bf16x8 pa[4];
#pragma unroll
            for (int mi = 0; mi < 4; ++mi)
                pa[mi] = *(const bf16x8*)qk_ptr(qb, mi * 16 + lo, hi * 8);
#pragma unroll
            for (int nd = 0; nd < 2; ++nd) {
                bf16x8 vb = *(const bf16x8*)vt_ptr(&s_vt[h][0], nd * 16 + lo, kk * 32 + hi * 8);
#pragma unroll
                for (int mi = 0; mi < 4; ++mi)
                    oacc[mi][nd] = __builtin_amdgcn_mfma_f32_16x16x32_bf16(
                        pa[mi], vb, oacc[mi][nd], 0, 0, 0);
            }
        }

        // scatter head output into ao (overlays k; safe after the inner barrier)
#pragma unroll
        for (int mi = 0; mi < 4; ++mi)
#pragma unroll
            for (int nd = 0; nd < 2; ++nd)
#pragma unroll
                for (int r = 0; r < 4; ++r)
                    *ao_ptr(s_kao, mi * 16 + hi * 4 + r, h * 32 + nd * 16 + lo) =
                        (bf16)oacc[mi][nd][r];
    }
    __syncthreads();

    // ============ Phase 3: out = ao @ out_w^T + out_b ============
    {
        bf16x8 fb[2][6];
#pragma unroll
        for (int t2 = 0; t2 < 2; ++t2)
#pragma unroll
            for (int kk = 0; kk < 6; ++kk)
                fb[t2][kk] = *(const bf16x8*)(out_wb + ((wv * 2 + t2) * 16 + lo) * 192 + kk * 32 + hi * 8);

        f32x4 facc[2][4];
#pragma unroll
        for (int t2 = 0; t2 < 2; ++t2)
#pragma unroll
            for (int mi = 0; mi < 4; ++mi) facc[t2][mi] = (f32x4){0.f, 0.f, 0.f, 0.f};

#pragma unroll
        for (int kk = 0; kk < 6; ++kk) {
            bf16x8 fa[4];
#pragma unroll
            for (int mi = 0; mi < 4; ++mi)
                fa[mi] = *(const bf16x8*)ao_ptr(s_kao, mi * 16 + lo, kk * 32 + hi * 8);
#pragma unroll
            for (int t2 = 0; t2 < 2; ++t2)
#pragma unroll
                for (int mi = 0; mi < 4; ++mi)
                    facc[t2][mi] = __builtin_amdgcn_mfma_f32_16x16x32_bf16(
                        fa[mi], fb[t2][kk], facc[t2][mi], 0, 0, 0);
        }

        float* ow = out + (size_t)b * 9408;
#pragma unroll
        for (int t2 = 0; t2 < 2; ++t2) {
            const int o2 = (wv * 2 + t2) * 16 + lo;
            const float ob = out_b[o2];
#pragma unroll
            for (int mi = 0; mi < 4; ++mi)
#pragma unroll
                for (int r = 0; r < 4; ++r) {
                    const int n = mi * 16 + hi * 4 + r;
                    if (n < 49) ow[n * 192 + o2] = facc[t2][mi][r] + ob;
                }
        }
    }
}

extern "C" void kernel_launch(void* const* d_in, const int* in_sizes, int n_in,
                              void* d_out, int out_size, void* d_ws, size_t ws_size,
                              hipStream_t stream) {
    const float* x      = (const float*)d_in[0];
    const float* mask   = (const float*)d_in[1];
    const float* qkv_w  = (const float*)d_in[2];
    const float* qkv_b  = (const float*)d_in[3];
    const float* out_w  = (const float*)d_in[4];
    const float* out_b  = (const float*)d_in[5];
    const float* rpb    = (const float*)d_in[6];
    float* out          = (float*)d_out;

    char* ws = (char*)d_ws;
    bf16*  qkv_wb = (bf16*)ws;                          // 110592 * 2 = 221184 B
    bf16*  out_wb = (bf16*)(ws + 221184);               //  36864 * 2 =  73728 B
    float* rpbx   = (float*)(ws + 221184 + 73728);      //  14406 * 4 =  57624 B

    hipLaunchKernelGGL(wmsa_prep, dim3(432), dim3(256), 0, stream,
                       qkv_w, out_w, rpb, qkv_wb, out_wb, rpbx);
    hipLaunchKernelGGL(wmsa_main, dim3(4096), dim3(384), 0, stream,
                       x, mask, qkv_b, out_b, qkv_wb, out_wb, rpbx, out);
}

// Round 3
// 660.619 us; speedup vs baseline: 1.5702x; 1.5702x over previous
//
#include <hip/hip_runtime.h>
#include <hip/hip_bf16.h>

typedef __bf16 bf16;
typedef __bf16 bf16x8 __attribute__((ext_vector_type(8)));
typedef float f32x4 __attribute__((ext_vector_type(4)));
typedef float floatv4 __attribute__((ext_vector_type(4)));

#define QK_SCALE 0.17677669529663687f

// ---- swizzled LDS addressing -------------------------------------------------
// qp/k tiles: [64][32] bf16 per head (row = 64B = 4 x 16B chunks).
__device__ __forceinline__ bf16* qk_ptr(bf16* base, int row, int col) {
    return base + row * 32 + ((((col >> 3) ^ ((row >> 1) & 3)) << 3)) + (col & 7);
}
// vt tile: [32][64] bf16 per head (row = 128B = 8 chunks). chunk' = chunk ^ (row&7).
__device__ __forceinline__ bf16* vt_ptr(bf16* base, int row, int col) {
    return base + row * 64 + ((((col >> 3) ^ (row & 7)) << 3)) + (col & 7);
}
// ao tile: [64][192] bf16 (row = 384B = 24 chunks). chunk' = chunk ^ (row&7).
__device__ __forceinline__ bf16* ao_ptr(bf16* base, int row, int col) {
    return base + row * 192 + ((((col >> 3) ^ (row & 7)) << 3)) + (col & 7);
}

// ---------------- prep: weight bf16 convert + rpb expand + combo table --------
__global__ void wmsa_prep(const float* __restrict__ qkv_w,
                          const float* __restrict__ out_w,
                          const float* __restrict__ rpb_table,
                          const float* __restrict__ mask,
                          bf16* __restrict__ qkv_wb,
                          bf16* __restrict__ out_wb,
                          float* __restrict__ rpbx,
                          float* __restrict__ combo,
                          int build_combo) {
    int t = blockIdx.x * 256 + threadIdx.x;
    if (t < 110592) qkv_wb[t] = (bf16)qkv_w[t];
    if (t < 36864)  out_wb[t] = (bf16)out_w[t];
    if (t < 14406) {
        int h = t / 2401, ij = t % 2401, i = ij / 49, j = ij % 49;
        int ri = (i / 7 - j / 7 + 6) * 13 + (i % 7 - j % 7 + 6);
        rpbx[t] = rpb_table[ri * 6 + h];
    }
    if (build_combo && t < 64 * 6 * 64 * 64) {
        int j = t & 63, i = (t >> 6) & 63, r = t >> 12;
        int h = r % 6, w = r / 6;
        float v = -1e30f;
        if (i < 49 && j < 49) {
            int ri = (i / 7 - j / 7 + 6) * 13 + (i % 7 - j % 7 + 6);
            v = rpb_table[ri * 6 + h] + mask[w * 2401 + i * 49 + j];
        }
        combo[t] = v;
    }
}

// ---------------- main fused kernel: one window per block ----------------
template <bool USE_COMBO>
__global__ __launch_bounds__(384, 4) void wmsa_main(
    const float* __restrict__ x, const float* __restrict__ mask,
    const float* __restrict__ qkv_b, const float* __restrict__ out_b,
    const bf16* __restrict__ qkv_wb, const bf16* __restrict__ out_wb,
    const float* __restrict__ rpbx, const float* __restrict__ combo,
    float* __restrict__ out)
{
    // q (later p): 6 heads x [64][32]; k (later ao[64][192]); v^T: 6 x [32][64]
    __shared__ bf16 s_qp[6][2048];
    __shared__ bf16 s_kao[12288];
    __shared__ bf16 s_vt[6][2048];

    const int b    = blockIdx.x;
    const int tid  = threadIdx.x;
    const int wv   = tid >> 6;      // 0..5
    const int lane = tid & 63;
    const int lo   = lane & 15;
    const int hi   = lane >> 4;     // 0..3

    const float* xw    = x + (size_t)b * 9408;
    const int    obase = wv * 96;
    const int    sec   = wv >> 1;   // 0=q 1=k 2=v

    // ============ Phase 1: QKV = x @ qkv_w^T + qkv_b ============
#pragma unroll 1
    for (int mib = 0; mib < 2; ++mib) {
        f32x4 acc[2][6];
#pragma unroll
        for (int mi = 0; mi < 2; ++mi)
#pragma unroll
            for (int nj = 0; nj < 6; ++nj) acc[mi][nj] = (f32x4){0.f, 0.f, 0.f, 0.f};

        const int r0 = mib * 32 + lo;        // always < 49
        const int r1 = r0 + 16;              // mib=1: valid only if < 49

        auto loadA = [&](bf16x8& d0, bf16x8& d1, int kk) {
            const float* p0 = xw + r0 * 192 + kk * 32 + hi * 8;
            floatv4 f0 = *(const floatv4*)p0;
            floatv4 f1 = *(const floatv4*)(p0 + 4);
            d0[0]=(bf16)f0[0]; d0[1]=(bf16)f0[1]; d0[2]=(bf16)f0[2]; d0[3]=(bf16)f0[3];
            d0[4]=(bf16)f1[0]; d0[5]=(bf16)f1[1]; d0[6]=(bf16)f1[2]; d0[7]=(bf16)f1[3];
            floatv4 g0 = {0.f,0.f,0.f,0.f}, g1 = {0.f,0.f,0.f,0.f};
            if (r1 < 49) {
                const float* p1 = xw + r1 * 192 + kk * 32 + hi * 8;
                g0 = *(const floatv4*)p1;
                g1 = *(const floatv4*)(p1 + 4);
            }
            d1[0]=(bf16)g0[0]; d1[1]=(bf16)g0[1]; d1[2]=(bf16)g0[2]; d1[3]=(bf16)g0[3];
            d1[4]=(bf16)g1[0]; d1[5]=(bf16)g1[1]; d1[6]=(bf16)g1[2]; d1[7]=(bf16)g1[3];
        };

        bf16x8 a0, a1, na0, na1;
        loadA(a0, a1, 0);
#pragma unroll
        for (int kk = 0; kk < 6; ++kk) {
            if (kk < 5) loadA(na0, na1, kk + 1);
#pragma unroll
            for (int nj = 0; nj < 6; ++nj) {
                const int o = obase + nj * 16 + lo;
                bf16x8 bfr = *(const bf16x8*)(qkv_wb + o * 192 + kk * 32 + hi * 8);
                acc[0][nj] = __builtin_amdgcn_mfma_f32_16x16x32_bf16(a0, bfr, acc[0][nj], 0, 0, 0);
                acc[1][nj] = __builtin_amdgcn_mfma_f32_16x16x32_bf16(a1, bfr, acc[1][nj], 0, 0, 0);
            }
            a0 = na0; a1 = na1;
        }

        // epilogue: bias + scatter into q / k / v^T LDS tiles
#pragma unroll
        for (int nj = 0; nj < 6; ++nj) {
            const int o    = obase + nj * 16 + lo;
            const float bs = qkv_b[o];
            const int oc   = o - sec * 192;
            const int hh   = oc >> 5;
            const int dd   = oc & 31;
#pragma unroll
            for (int mi = 0; mi < 2; ++mi)
#pragma unroll
                for (int r = 0; r < 4; ++r) {
                    const int n = mib * 32 + mi * 16 + hi * 4 + r;
                    const float v = acc[mi][nj][r] + bs;
                    if (sec == 0)      *qk_ptr(&s_qp[hh][0], n, dd)      = (bf16)(v * QK_SCALE);
                    else if (sec == 1) *qk_ptr(s_kao + hh * 2048, n, dd) = (bf16)v;
                    else               *vt_ptr(&s_vt[hh][0], dd, n)      = (bf16)v;
                }
        }
    }
    __syncthreads();

    // ============ Phase 2: attention, head h = wave id ============
    {
        const int h = wv;
        bf16* qb = &s_qp[h][0];
        bf16* kbase = s_kao + h * 2048;

        bf16x8 qa[4], kb[4];
#pragma unroll
        for (int mi = 0; mi < 4; ++mi)
            qa[mi] = *(const bf16x8*)qk_ptr(qb, mi * 16 + lo, hi * 8);
#pragma unroll
        for (int nt = 0; nt < 4; ++nt)
            kb[nt] = *(const bf16x8*)qk_ptr(kbase, nt * 16 + lo, hi * 8);

        f32x4 s[4][4];
#pragma unroll
        for (int mi = 0; mi < 4; ++mi)
#pragma unroll
            for (int nt = 0; nt < 4; ++nt) s[mi][nt] = (f32x4){0.f, 0.f, 0.f, 0.f};
#pragma unroll
        for (int mi = 0; mi < 4; ++mi)
#pragma unroll
            for (int nt = 0; nt < 4; ++nt)
                s[mi][nt] = __builtin_amdgcn_mfma_f32_16x16x32_bf16(
                    qa[mi], kb[nt], s[mi][nt], 0, 0, 0);

        // bias + mask
        if (USE_COMBO) {
            const float* cb = combo + (((size_t)(b & 63) * 6 + h) << 12);
#pragma unroll
            for (int nt = 0; nt < 4; ++nt) {
                const int j = nt * 16 + lo;
#pragma unroll
                for (int mi = 0; mi < 4; ++mi)
#pragma unroll
                    for (int r = 0; r < 4; ++r) {
                        const int i = mi * 16 + hi * 4 + r;
                        s[mi][nt][r] += cb[i * 64 + j];
                    }
            }
        } else {
            const float* mk = mask + (size_t)(b & 63) * 2401;
            const float* rb = rpbx + h * 2401;
#pragma unroll
            for (int nt = 0; nt < 4; ++nt) {
                const int j = nt * 16 + lo;
#pragma unroll
                for (int mi = 0; mi < 4; ++mi)
#pragma unroll
                    for (int r = 0; r < 4; ++r) {
                        const int i = mi * 16 + hi * 4 + r;
                        float sv = s[mi][nt][r];
                        if (j >= 49) sv = -1e30f;
                        else if (i < 49) sv += rb[i * 49 + j] + mk[i * 49 + j];
                        s[mi][nt][r] = sv;
                    }
            }
        }

        // softmax over j (64 cols = 4 regs x 16 lanes sharing hi)
#pragma unroll
        for (int mi = 0; mi < 4; ++mi)
#pragma unroll
            for (int r = 0; r < 4; ++r) {
                float m = fmaxf(fmaxf(s[mi][0][r], s[mi][1][r]),
                                fmaxf(s[mi][2][r], s[mi][3][r]));
                m = fmaxf(m, __shfl_xor(m, 1));
                m = fmaxf(m, __shfl_xor(m, 2));
                m = fmaxf(m, __shfl_xor(m, 4));
                m = fmaxf(m, __shfl_xor(m, 8));
                float sum = 0.f;
#pragma unroll
                for (int nt = 0; nt < 4; ++nt) {
                    float p = __expf(s[mi][nt][r] - m);
                    s[mi][nt][r] = p;
                    sum += p;
                }
                sum += __shfl_xor(sum, 1);
                sum += __shfl_xor(sum, 2);
                sum += __shfl_xor(sum, 4);
                sum += __shfl_xor(sum, 8);
                const float inv = 1.0f / sum;
#pragma unroll
                for (int nt = 0; nt < 4; ++nt) s[mi][nt][r] *= inv;
            }

        // all waves' q/k LDS reads happened before this point -> overlay safe
        __syncthreads();

        // PV: O_h = P(64x64) @ V_h(64x32); P staged into qp[h] (q is dead)
        f32x4 oacc[4][2];
#pragma unroll
        for (int mi = 0; mi < 4; ++mi)
#pragma unroll
            for (int nd = 0; nd < 2; ++nd) oacc[mi][nd] = (f32x4){0.f, 0.f, 0.f, 0.f};

#pragma unroll 1
        for (int kk = 0; kk < 2; ++kk) {
#pragma unroll
            for (int mi = 0; mi < 4; ++mi)
#pragma unroll
                for (int c = 0; c < 2; ++c) {
                    const int nt = kk * 2 + c;
#pragma unroll
                    for (int r = 0; r < 4; ++r)
                        *qk_ptr(qb, mi * 16 + hi * 4 + r, c * 16 + lo) = (bf16)s[mi][nt][r];
                }
            bf16x8 pa[4];
#pragma unroll
            for (int mi = 0; mi < 4; ++mi)
                pa[mi] = *(const bf16x8*)qk_ptr(qb, mi * 16 + lo, hi * 8);
#pragma unroll
            for (int nd = 0; nd < 2; ++nd) {
                bf16x8 vb = *(const bf16x8*)vt_ptr(&s_vt[h][0], nd * 16 + lo, kk * 32 + hi * 8);
#pragma unroll
                for (int mi = 0; mi < 4; ++mi)
                    oacc[mi][nd] = __builtin_amdgcn_mfma_f32_16x16x32_bf16(
                        pa[mi], vb, oacc[mi][nd], 0, 0, 0);
            }
        }

        // scatter head output into ao (overlays k; safe after the inner barrier)
#pragma unroll
        for (int mi = 0; mi < 4; ++mi)
#pragma unroll
            for (int nd = 0; nd < 2; ++nd)
#pragma unroll
                for (int r = 0; r < 4; ++r)
                    *ao_ptr(s_kao, mi * 16 + hi * 4 + r, h * 32 + nd * 16 + lo) =
                        (bf16)oacc[mi][nd][r];
    }
    __syncthreads();

    // ============ Phase 3: out = ao @ out_w^T + out_b ============
    {
        f32x4 facc[2][4];
#pragma unroll
        for (int t2 = 0; t2 < 2; ++t2)
#pragma unroll
            for (int mi = 0; mi < 4; ++mi) facc[t2][mi] = (f32x4){0.f, 0.f, 0.f, 0.f};

#pragma unroll
        for (int kk = 0; kk < 6; ++kk) {
            bf16x8 fa[4];
#pragma unroll
            for (int mi = 0; mi < 4; ++mi)
                fa[mi] = *(const bf16x8*)ao_ptr(s_kao, mi * 16 + lo, kk * 32 + hi * 8);
            bf16x8 fb0 = *(const bf16x8*)(out_wb + ((wv * 2 + 0) * 16 + lo) * 192 + kk * 32 + hi * 8);
            bf16x8 fb1 = *(const bf16x8*)(out_wb + ((wv * 2 + 1) * 16 + lo) * 192 + kk * 32 + hi * 8);
#pragma unroll
            for (int mi = 0; mi < 4; ++mi) {
                facc[0][mi] = __builtin_amdgcn_mfma_f32_16x16x32_bf16(fa[mi], fb0, facc[0][mi], 0, 0, 0);
                facc[1][mi] = __builtin_amdgcn_mfma_f32_16x16x32_bf16(fa[mi], fb1, facc[1][mi], 0, 0, 0);
            }
        }

        float* ow = out + (size_t)b * 9408;
#pragma unroll
        for (int t2 = 0; t2 < 2; ++t2) {
            const int o2 = (wv * 2 + t2) * 16 + lo;
            const float ob = out_b[o2];
#pragma unroll
            for (int mi = 0; mi < 4; ++mi)
#pragma unroll
                for (int r = 0; r < 4; ++r) {
                    const int n = mi * 16 + hi * 4 + r;
                    if (n < 49) ow[n * 192 + o2] = facc[t2][mi][r] + ob;
                }
        }
    }
}

extern "C" void kernel_launch(void* const* d_in, const int* in_sizes, int n_in,
                              void* d_out, int out_size, void* d_ws, size_t ws_size,
                              hipStream_t stream) {
    const float* x      = (const float*)d_in[0];
    const float* mask   = (const float*)d_in[1];
    const float* qkv_w  = (const float*)d_in[2];
    const float* qkv_b  = (const float*)d_in[3];
    const float* out_w  = (const float*)d_in[4];
    const float* out_b  = (const float*)d_in[5];
    const float* rpb    = (const float*)d_in[6];
    float* out          = (float*)d_out;

    char* ws = (char*)d_ws;
    bf16*  qkv_wb = (bf16*)ws;                       // 110592 * 2 = 221184 B
    bf16*  out_wb = (bf16*)(ws + 221184);            //  36864 * 2 =  73728 B
    float* rpbx   = (float*)(ws + 294912);           //  14406 * 4 =  57624 B
    float* combo  = (float*)(ws + 352768);           // 1572864 * 4 = 6291456 B
    const bool use_combo = ws_size >= (size_t)(352768 + 6291456);

    hipLaunchKernelGGL(wmsa_prep, dim3(6144), dim3(256), 0, stream,
                       qkv_w, out_w, rpb, mask, qkv_wb, out_wb, rpbx, combo,
                       use_combo ? 1 : 0);
    if (use_combo)
        hipLaunchKernelGGL(HIP_KERNEL_NAME(wmsa_main<true>), dim3(4096), dim3(384), 0, stream,
                           x, mask, qkv_b, out_b, qkv_wb, out_wb, rpbx, combo, out);
    else
        hipLaunchKernelGGL(HIP_KERNEL_NAME(wmsa_main<false>), dim3(4096), dim3(384), 0, stream,
                           x, mask, qkv_b, out_b, qkv_wb, out_wb, rpbx, combo, out);
}